// Round 7
// baseline (175.200 us; speedup 1.0000x reference)
//
#include <hip/hip_runtime.h>
#include <stdint.h>

#define NN 100000
#define NE 1600000
#define C  128
#define NB 782          // buckets of 128 dst nodes: 782*128 = 100096 >= NN
#define CAP 4096        // per-bucket edge capacity (mean 2048, sigma ~45)
#define SB_SHIFT 13     // src coarse-slice key in phase2 sort
#define MB 782          // front GEMM blocks: 128 rows each
#define P1B 250         // phase1 blocks (6400 edges each)

typedef __attribute__((ext_vector_type(8))) short short8;
typedef __attribute__((ext_vector_type(4))) float f32x4;

__device__ __forceinline__ float bf2f(uint16_t u) {
  union { uint32_t u; float f; } v; v.u = ((uint32_t)u) << 16; return v.f;
}
__device__ __forceinline__ uint16_t f2bf(float f) {
  union { float f; uint32_t u; } v; v.f = f;
  uint32_t r = v.u + 0x7fffu + ((v.u >> 16) & 1u);   // RNE
  return (uint16_t)(r >> 16);
}

// ---------------- cast the 3 weight matrices in one dispatch ----------------
__global__ __launch_bounds__(256) void cast3_k(
    const float* __restrict__ a, const float* __restrict__ b, const float* __restrict__ c,
    uint16_t* __restrict__ oa, uint16_t* __restrict__ ob, uint16_t* __restrict__ oc)
{
  int i = blockIdx.x * 256 + threadIdx.x;     // 3 * 4096 float4-groups
  int which = i >> 12, j = i & 4095;
  const float* s = which == 0 ? a : (which == 1 ? b : c);
  uint16_t* d    = which == 0 ? oa : (which == 1 ? ob : oc);
  float4 v = ((const float4*)s)[j];
  uint2 p;
  p.x = (uint32_t)f2bf(v.x) | ((uint32_t)f2bf(v.y) << 16);
  p.y = (uint32_t)f2bf(v.z) | ((uint32_t)f2bf(v.w) << 16);
  ((uint2*)d)[j] = p;
}

// LDS weight tile: 16B chunk (c, k16) at byte c*256 + ((k16 ^ (c&15))<<4).
// Read of frag (c, kk, g) -> slot (kk*4+g)^(c&15): conflict-free b128 pattern.

// ------- fused front: blocks [0,MB): h = relu(x@Wp^T+bp), r = x@Wr^T+bl -----
//         blocks [MB,MB+P1B): phase1 edge bucketing (independent work)
__global__ __launch_bounds__(512) void fused_front_k(
    const float* __restrict__ x, const uint16_t* __restrict__ wpb,
    const uint16_t* __restrict__ wrb,
    const float* __restrict__ bp, const float* __restrict__ bl,
    uint16_t* __restrict__ h, uint16_t* __restrict__ rb,
    const int* __restrict__ esrc, const int* __restrict__ edst,
    int* __restrict__ gcnt, uint32_t* __restrict__ ebuf)
{
  extern __shared__ uint8_t slds[];
  const int t = threadIdx.x;

  if (blockIdx.x < MB) {
    // stage Wp at 0, Wr at +32KB
#pragma unroll
    for (int qq = 0; qq < 4; ++qq) {
      int ci = qq * 512 + t;
      int c = ci >> 4, k16 = ci & 15;
      int slot = (k16 ^ (c & 15)) << 4;
      *(short8*)(slds + c * 256 + slot)         = *(const short8*)(wpb + ci * 8);
      *(short8*)(slds + 32768 + c * 256 + slot) = *(const short8*)(wrb + ci * 8);
    }
    __syncthreads();

    const int w = t >> 6, lane = t & 63;
    const int tile_m = blockIdx.x * 128 + w * 16;
    if (tile_m >= NN) return;
    const int r16 = lane & 15, g = lane >> 4;

    int arow = tile_m + r16; if (arow >= NN) arow = NN - 1;   // clamp OOB read
    short8 a[4];
    const float* xp = x + (size_t)arow * C + g * 8;
#pragma unroll
    for (int kk = 0; kk < 4; ++kk) {
      float4 u = *(const float4*)(xp + kk * 32);
      float4 v = *(const float4*)(xp + kk * 32 + 4);
      short8 av;
      av[0] = (short)f2bf(u.x); av[1] = (short)f2bf(u.y);
      av[2] = (short)f2bf(u.z); av[3] = (short)f2bf(u.w);
      av[4] = (short)f2bf(v.x); av[5] = (short)f2bf(v.y);
      av[6] = (short)f2bf(v.z); av[7] = (short)f2bf(v.w);
      a[kk] = av;
    }

#pragma unroll
    for (int nt = 0; nt < 8; ++nt) {
      f32x4 ap = {0.f, 0.f, 0.f, 0.f};
      f32x4 ar = {0.f, 0.f, 0.f, 0.f};
      const int c = nt * 16 + r16;
      const uint8_t* rbp = slds + c * 256;
      const uint8_t* rbr = slds + 32768 + c * 256;
#pragma unroll
      for (int kk = 0; kk < 4; ++kk) {
        int slot = (((kk << 2) + g) ^ (c & 15)) << 4;
        ap = __builtin_amdgcn_mfma_f32_16x16x32_bf16(a[kk], *(const short8*)(rbp + slot), ap, 0, 0, 0);
        ar = __builtin_amdgcn_mfma_f32_16x16x32_bf16(a[kk], *(const short8*)(rbr + slot), ar, 0, 0, 0);
      }
      const float bpv = bp[c], blv = bl[c];
#pragma unroll
      for (int rr = 0; rr < 4; ++rr) {
        int row = tile_m + g * 4 + rr;       // C/D: col=lane&15, row=(lane>>4)*4+rr
        if (row < NN) {                      // guard: no overflow past NN (race fix)
          float vh = ap[rr] + bpv;
          vh = vh > 0.f ? vh : 0.f;
          h[(size_t)row * C + c]  = f2bf(vh);
          rb[(size_t)row * C + c] = f2bf(ar[rr] + blv);
        }
      }
    }
  } else {
    // ---------------- phase1 role: bucket edges by dst>>7 ----------------
    int* bh = (int*)slds;                     // NB ints: histogram / cursor
    int* gb = bh + NB;                        // NB ints: reserved base
    const int blk = blockIdx.x - MB;
    const int base = blk * 6400;              // 1600 int4 per block

    for (int i = t; i < NB; i += 512) bh[i] = 0;

    const int4* ed4 = (const int4*)(edst + base);
    const int4* es4 = (const int4*)(esrc + base);
    int4 dv[4], sv[4];
    bool val[4];
#pragma unroll
    for (int k = 0; k < 4; ++k) {
      int i = t + k * 512;
      val[k] = (i < 1600);
      if (val[k]) { dv[k] = ed4[i]; sv[k] = es4[i]; }
    }
    __syncthreads();

#pragma unroll
    for (int k = 0; k < 4; ++k) if (val[k]) {
      atomicAdd(&bh[dv[k].x >> 7], 1); atomicAdd(&bh[dv[k].y >> 7], 1);
      atomicAdd(&bh[dv[k].z >> 7], 1); atomicAdd(&bh[dv[k].w >> 7], 1);
    }
    __syncthreads();

    for (int i = t; i < NB; i += 512) {
      int c = bh[i];
      gb[i] = c ? atomicAdd(&gcnt[i], c) : 0;
      bh[i] = 0;                              // reuse as local cursor
    }
    __syncthreads();

#define P1_SCATTER(d, s) do { \
      int bb = (d) >> 7; \
      int o = atomicAdd(&bh[bb], 1); \
      int pos = gb[bb] + o; \
      if (pos < CAP) ebuf[(size_t)bb * CAP + pos] = ((uint32_t)((d) & 127) << 17) | (uint32_t)(s); \
    } while (0)

#pragma unroll
    for (int k = 0; k < 4; ++k) if (val[k]) {
      P1_SCATTER(dv[k].x, sv[k].x); P1_SCATTER(dv[k].y, sv[k].y);
      P1_SCATTER(dv[k].z, sv[k].z); P1_SCATTER(dv[k].w, sv[k].w);
    }
#undef P1_SCATTER
  }
}

// ---------------- exclusive scan (1 block) over NB bucket counts ------------
__global__ __launch_bounds__(1024) void scan_block_k(
    const int* __restrict__ in, int* __restrict__ out, int n)
{
  __shared__ int sm[1024];
  int t = threadIdx.x;
  int v = (t < n) ? in[t] : 0;
  sm[t] = v;
  __syncthreads();
  for (int off = 1; off < 1024; off <<= 1) {
    int x = (t >= off) ? sm[t - off] : 0;
    __syncthreads();
    sm[t] += x;
    __syncthreads();
  }
  if (t < n) out[t] = sm[t] - v;            // exclusive
}

// ------- phase 2: per-bucket LDS sort by (local_dst, src>>13) ---------------
__global__ __launch_bounds__(256) void phase2_k(
    const uint32_t* __restrict__ ebuf, const int* __restrict__ gcnt,
    const int* __restrict__ gbase, int* __restrict__ ssrc,
    int* __restrict__ start, int* __restrict__ deg)
{
  __shared__ uint32_t raw[CAP];
  __shared__ int lout[CAP];
  __shared__ int cnt2[128 * 16];
  __shared__ int nd[128];
  const int b = blockIdx.x, t = threadIdx.x;
  const int n0 = b * 128;
  int cnt = gcnt[b]; if (cnt > CAP) cnt = CAP;
  const int base = gbase[b];

  for (int i = t; i < 128 * 16; i += 256) cnt2[i] = 0;
  __syncthreads();
  for (int i = t; i < cnt; i += 256) {
    uint32_t v = ebuf[(size_t)b * CAP + i];
    raw[i] = v;
    atomicAdd(&cnt2[(v >> 17) * 16 + ((v & 0x1FFFFu) >> SB_SHIFT)], 1);
  }
  __syncthreads();

  int deg_t = 0;
  if (t < 128) {
#pragma unroll
    for (int i = 0; i < 16; ++i) deg_t += cnt2[t * 16 + i];
    nd[t] = deg_t;
  }
  __syncthreads();
  for (int off = 1; off < 128; off <<= 1) {
    int v = 0;
    if (t < 128 && t >= off) v = nd[t - off];
    __syncthreads();
    if (t < 128) nd[t] += v;
    __syncthreads();
  }
  if (t < 128) {
    int pref = nd[t] - deg_t;               // exclusive
    if (n0 + t < NN) { start[n0 + t] = base + pref; deg[n0 + t] = deg_t; }
    int run = pref;
#pragma unroll
    for (int i = 0; i < 16; ++i) { int c = cnt2[t * 16 + i]; cnt2[t * 16 + i] = run; run += c; }
  }
  __syncthreads();
  for (int i = t; i < cnt; i += 256) {
    uint32_t v = raw[i];
    int o = atomicAdd(&cnt2[(v >> 17) * 16 + ((v & 0x1FFFFu) >> SB_SHIFT)], 1);
    lout[o] = (int)(v & 0x1FFFFu);
  }
  __syncthreads();
  for (int i = t; i < cnt; i += 256) ssrc[base + i] = lout[i];
}

// ------- fused back: gather-aggregate -> LDS tile -> MFMA(agg@Wl) + r + LN --
// 256 thr = 4 waves x 16 rows = 64 rows/block. LDS: Wl 32KB + tile 16KB = 48KB
// Gather: slot-per-node (4 nodes concurrent/wave), 8 uint4 loads in flight/lane.
__global__ __launch_bounds__(256) void fused_back_k(
    const uint16_t* __restrict__ h, const int* __restrict__ ssrc,
    const int* __restrict__ start, const int* __restrict__ deg,
    const uint16_t* __restrict__ wlb, const uint16_t* __restrict__ rb,
    const float* __restrict__ gamma, const float* __restrict__ beta,
    float* __restrict__ out)
{
  __shared__ uint8_t wl[32768];
  __shared__ uint8_t tile[16384];   // 64 rows x 128 ch bf16, slot-swizzled
  const int t = threadIdx.x;

#pragma unroll
  for (int qq = 0; qq < 8; ++qq) {            // stage Wl: 2048 chunks / 256 thr
    int ci = qq * 256 + t;
    int c = ci >> 4, k16 = ci & 15;
    *(short8*)(wl + c * 256 + ((k16 ^ (c & 15)) << 4)) = *(const short8*)(wlb + ci * 8);
  }
  __syncthreads();

  const int w = t >> 6, lane = t & 63;
  const int q = lane >> 4, l16 = lane & 15;   // slot q handles nodes m*4+q
  const int row_base = blockIdx.x * 64 + w * 16;

#define ACC8(v) do { \
    a[0] += bf2f((uint16_t)(v).x); a[1] += bf2f((uint16_t)((v).x >> 16)); \
    a[2] += bf2f((uint16_t)(v).y); a[3] += bf2f((uint16_t)((v).y >> 16)); \
    a[4] += bf2f((uint16_t)(v).z); a[5] += bf2f((uint16_t)((v).z >> 16)); \
    a[6] += bf2f((uint16_t)(v).w); a[7] += bf2f((uint16_t)((v).w >> 16)); \
  } while (0)

#pragma unroll
  for (int m = 0; m < 4; ++m) {
    const int rrow = m * 4 + q;               // 0..15 within wave tile
    const int n = row_base + rrow;
    const int cnt = (n < NN) ? deg[n] : 0;
    const int s0  = (n < NN) ? start[n] : 0;
    float a[8];
#pragma unroll
    for (int i = 0; i < 8; ++i) a[i] = 0.f;

    for (int j = 0; j < cnt; j += 8) {        // 8 gathers in flight per lane
      int e[8];
#pragma unroll
      for (int k = 0; k < 8; ++k) {
        int idx = j + k; if (idx >= cnt) idx = cnt - 1;
        e[k] = ssrc[s0 + idx];
      }
      uint4 vv[8];
#pragma unroll
      for (int k = 0; k < 8; ++k)
        vv[k] = *(const uint4*)(h + (size_t)e[k] * C + (size_t)l16 * 8);
#pragma unroll
      for (int k = 0; k < 8; ++k)
        if (j + k < cnt) ACC8(vv[k]);
    }
    // pack 8 ch -> bf16x8, write swizzled tile row (wave-private region)
    uint4 p;
    p.x = (uint32_t)f2bf(a[0]) | ((uint32_t)f2bf(a[1]) << 16);
    p.y = (uint32_t)f2bf(a[2]) | ((uint32_t)f2bf(a[3]) << 16);
    p.z = (uint32_t)f2bf(a[4]) | ((uint32_t)f2bf(a[5]) << 16);
    p.w = (uint32_t)f2bf(a[6]) | ((uint32_t)f2bf(a[7]) << 16);
    *(uint4*)(tile + (size_t)(w * 16 + rrow) * 256 + ((l16 ^ rrow) << 4)) = p;
  }
#undef ACC8

  // ---- MFMA: out_pre = agg @ Wl^T + r; rows are this wave's own tile rows --
  const int r16 = lane & 15, g = lane >> 4;
  short8 af[4];
#pragma unroll
  for (int kk = 0; kk < 4; ++kk)
    af[kk] = *(const short8*)(tile + (size_t)(w * 16 + r16) * 256 +
                              ((((kk << 2) + g) ^ r16) << 4));

  f32x4 acc[8];
#pragma unroll
  for (int nt = 0; nt < 8; ++nt) {
    f32x4 c4 = {0.f, 0.f, 0.f, 0.f};
    const int c = nt * 16 + r16;
    const uint8_t* rbl = wl + c * 256;
#pragma unroll
    for (int kk = 0; kk < 4; ++kk) {
      short8 b = *(const short8*)(rbl + ((((kk << 2) + g) ^ (c & 15)) << 4));
      c4 = __builtin_amdgcn_mfma_f32_16x16x32_bf16(af[kk], b, c4, 0, 0, 0);
    }
    // add r (x@Wr + bl computed in front)
#pragma unroll
    for (int rr = 0; rr < 4; ++rr) {
      int row = row_base + g * 4 + rr;
      float rv = (row < NN) ? bf2f(rb[(size_t)row * C + c]) : 0.f;
      c4[rr] += rv;
    }
    acc[nt] = c4;
  }

  // LayerNorm per row (row lives in one 16-lane group) -> shfl_xor 1,2,4,8
  float s1[4], s2[4];
#pragma unroll
  for (int rr = 0; rr < 4; ++rr) { s1[rr] = 0.f; s2[rr] = 0.f; }
#pragma unroll
  for (int nt = 0; nt < 8; ++nt)
#pragma unroll
    for (int rr = 0; rr < 4; ++rr) { float v = acc[nt][rr]; s1[rr] += v; s2[rr] += v * v; }
#pragma unroll
  for (int msk = 1; msk <= 8; msk <<= 1) {
#pragma unroll
    for (int rr = 0; rr < 4; ++rr) {
      s1[rr] += __shfl_xor(s1[rr], msk, 64);
      s2[rr] += __shfl_xor(s2[rr], msk, 64);
    }
  }
  float mean[4], rstd[4];
#pragma unroll
  for (int rr = 0; rr < 4; ++rr) {
    mean[rr] = s1[rr] * (1.f / C);
    float var = s2[rr] * (1.f / C) - mean[rr] * mean[rr];
    rstd[rr] = rsqrtf(var + 1e-5f);
  }
#pragma unroll
  for (int nt = 0; nt < 8; ++nt) {
    const int col = nt * 16 + r16;
    const float gmv = gamma[col], btv = beta[col];
#pragma unroll
    for (int rr = 0; rr < 4; ++rr) {
      int row = row_base + g * 4 + rr;
      if (row < NN)
        out[(size_t)row * C + col] = (acc[nt][rr] - mean[rr]) * rstd[rr] * gmv + btv;
    }
  }
}

// ---------------- launch ----------------
extern "C" void kernel_launch(void* const* d_in, const int* in_sizes, int n_in,
                              void* d_out, int out_size, void* d_ws, size_t ws_size,
                              hipStream_t stream)
{
  const float* x        = (const float*)d_in[0];
  const int* ei         = (const int*)d_in[1];     // int32 from harness
  const float* Wp       = (const float*)d_in[2];
  const float* bp       = (const float*)d_in[3];
  const float* Wl       = (const float*)d_in[4];
  const float* bl       = (const float*)d_in[5];
  const float* Wr       = (const float*)d_in[6];
  const float* gamma    = (const float*)d_in[7];
  const float* beta     = (const float*)d_in[8];
  float* out            = (float*)d_out;

  char* ws = (char*)d_ws;
  uint16_t* rb   = (uint16_t*)(ws + 0);          // 25,600,000  r = x@Wr^T + bl (bf16)
  uint16_t* h    = (uint16_t*)(ws + 25600000);   // 25,600,000  relu(proj) bf16
  uint32_t* ebuf = (uint32_t*)(ws + 51200000);   // 12,812,288  bucketed edges
  uint16_t* wpb  = (uint16_t*)(ws + 76800000);   // 32,768
  uint16_t* wlb  = (uint16_t*)(ws + 76832768);   // 32,768
  uint16_t* wrb  = (uint16_t*)(ws + 76865536);   // 32,768
  int* deg       = (int*)(ws + 76898304);        // 400,000
  int* start     = (int*)(ws + 77298304);        // 400,000
  int* gcnt      = (int*)(ws + 77698304);        // 3,128
  int* gbase     = (int*)(ws + 77702400);        // 3,128
  int* ssrc      = (int*)(ws + 78102400);        // 6,400,000

  const int* esrc = ei;        // edge_index[0]
  const int* edst = ei + NE;   // edge_index[1]

  hipMemsetAsync(gcnt, 0, NB * sizeof(int), stream);

  cast3_k<<<48, 256, 0, stream>>>(Wp, Wl, Wr, wpb, wlb, wrb);

  fused_front_k<<<MB + P1B, 512, 65536, stream>>>(
      x, wpb, wrb, bp, bl, h, rb, esrc, edst, gcnt, ebuf);

  scan_block_k<<<1, 1024, 0, stream>>>(gcnt, gbase, NB);
  phase2_k<<<NB, 256, 0, stream>>>(ebuf, gcnt, gbase, ssrc, start, deg);

  fused_back_k<<<(NN + 63) / 64, 256, 0, stream>>>(
      h, ssrc, start, deg, wlb, rb, gamma, beta, out);
}

// Round 8
// 141.100 us; speedup vs baseline: 1.2417x; 1.2417x over previous
//
#include <hip/hip_runtime.h>
#include <stdint.h>

#define NN 100000
#define NE 1600000
#define C  128
#define NB 782          // buckets of 128 dst nodes: 782*128 = 100096 >= NN
#define CAP 4096        // per-bucket edge capacity (mean 2048, sigma ~45)
#define SB_SHIFT 13     // src coarse-slice key in phase2 sort
#define MB 782          // front GEMM blocks: 128 rows each
#define P1B 250         // phase1 blocks (6400 edges each)

typedef __attribute__((ext_vector_type(8))) short short8;
typedef __attribute__((ext_vector_type(4))) float f32x4;

__device__ __forceinline__ float bf2f(uint16_t u) {
  union { uint32_t u; float f; } v; v.u = ((uint32_t)u) << 16; return v.f;
}
__device__ __forceinline__ uint16_t f2bf(float f) {
  union { float f; uint32_t u; } v; v.f = f;
  uint32_t r = v.u + 0x7fffu + ((v.u >> 16) & 1u);   // RNE
  return (uint16_t)(r >> 16);
}
__device__ __forceinline__ float2 bf2x2(uint32_t u) {
  return make_float2(bf2f((uint16_t)u), bf2f((uint16_t)(u >> 16)));
}

// ---------------- cast the 3 weight matrices in one dispatch ----------------
__global__ __launch_bounds__(256) void cast3_k(
    const float* __restrict__ a, const float* __restrict__ b, const float* __restrict__ c,
    uint16_t* __restrict__ oa, uint16_t* __restrict__ ob, uint16_t* __restrict__ oc)
{
  int i = blockIdx.x * 256 + threadIdx.x;     // 3 * 4096 float4-groups
  int which = i >> 12, j = i & 4095;
  const float* s = which == 0 ? a : (which == 1 ? b : c);
  uint16_t* d    = which == 0 ? oa : (which == 1 ? ob : oc);
  float4 v = ((const float4*)s)[j];
  uint2 p;
  p.x = (uint32_t)f2bf(v.x) | ((uint32_t)f2bf(v.y) << 16);
  p.y = (uint32_t)f2bf(v.z) | ((uint32_t)f2bf(v.w) << 16);
  ((uint2*)d)[j] = p;
}

// LDS weight tile: 16B chunk (c, k16) at byte c*256 + ((k16 ^ (c&15))<<4).
// Read of frag (c, kk, g) -> slot (kk*4+g)^(c&15): conflict-free b128 pattern.

// ------- fused front: blocks [0,MB): h = relu(x@Wp^T+bp), r = x@Wr^T+bl -----
//         blocks [MB,MB+P1B): phase1 edge bucketing (independent work)
__global__ __launch_bounds__(512) void fused_front_k(
    const float* __restrict__ x, const uint16_t* __restrict__ wpb,
    const uint16_t* __restrict__ wrb,
    const float* __restrict__ bp, const float* __restrict__ bl,
    uint16_t* __restrict__ h, uint16_t* __restrict__ rb,
    const int* __restrict__ esrc, const int* __restrict__ edst,
    int* __restrict__ gcnt, uint32_t* __restrict__ ebuf)
{
  extern __shared__ uint8_t slds[];
  const int t = threadIdx.x;

  if (blockIdx.x < MB) {
    // stage Wp at 0, Wr at +32KB
#pragma unroll
    for (int qq = 0; qq < 4; ++qq) {
      int ci = qq * 512 + t;
      int c = ci >> 4, k16 = ci & 15;
      int slot = (k16 ^ (c & 15)) << 4;
      *(short8*)(slds + c * 256 + slot)         = *(const short8*)(wpb + ci * 8);
      *(short8*)(slds + 32768 + c * 256 + slot) = *(const short8*)(wrb + ci * 8);
    }
    __syncthreads();

    const int w = t >> 6, lane = t & 63;
    const int tile_m = blockIdx.x * 128 + w * 16;
    if (tile_m >= NN) return;
    const int r16 = lane & 15, g = lane >> 4;

    int arow = tile_m + r16; if (arow >= NN) arow = NN - 1;   // clamp OOB read
    short8 a[4];
    const float* xp = x + (size_t)arow * C + g * 8;
#pragma unroll
    for (int kk = 0; kk < 4; ++kk) {
      float4 u = *(const float4*)(xp + kk * 32);
      float4 v = *(const float4*)(xp + kk * 32 + 4);
      short8 av;
      av[0] = (short)f2bf(u.x); av[1] = (short)f2bf(u.y);
      av[2] = (short)f2bf(u.z); av[3] = (short)f2bf(u.w);
      av[4] = (short)f2bf(v.x); av[5] = (short)f2bf(v.y);
      av[6] = (short)f2bf(v.z); av[7] = (short)f2bf(v.w);
      a[kk] = av;
    }

#pragma unroll
    for (int nt = 0; nt < 8; ++nt) {
      f32x4 ap = {0.f, 0.f, 0.f, 0.f};
      f32x4 ar = {0.f, 0.f, 0.f, 0.f};
      const int c = nt * 16 + r16;
      const uint8_t* rbp = slds + c * 256;
      const uint8_t* rbr = slds + 32768 + c * 256;
#pragma unroll
      for (int kk = 0; kk < 4; ++kk) {
        int slot = (((kk << 2) + g) ^ (c & 15)) << 4;
        ap = __builtin_amdgcn_mfma_f32_16x16x32_bf16(a[kk], *(const short8*)(rbp + slot), ap, 0, 0, 0);
        ar = __builtin_amdgcn_mfma_f32_16x16x32_bf16(a[kk], *(const short8*)(rbr + slot), ar, 0, 0, 0);
      }
      const float bpv = bp[c], blv = bl[c];
#pragma unroll
      for (int rr = 0; rr < 4; ++rr) {
        int row = tile_m + g * 4 + rr;       // C/D: col=lane&15, row=(lane>>4)*4+rr
        if (row < NN) {                      // guard: no overflow past NN
          float vh = ap[rr] + bpv;
          vh = vh > 0.f ? vh : 0.f;
          h[(size_t)row * C + c]  = f2bf(vh);
          rb[(size_t)row * C + c] = f2bf(ar[rr] + blv);
        }
      }
    }
  } else {
    // ---------------- phase1 role: bucket edges by dst>>7 ----------------
    int* bh = (int*)slds;                     // NB ints: histogram / cursor
    int* gb = bh + NB;                        // NB ints: reserved base
    const int blk = blockIdx.x - MB;
    const int base = blk * 6400;              // 1600 int4 per block

    for (int i = t; i < NB; i += 512) bh[i] = 0;

    const int4* ed4 = (const int4*)(edst + base);
    const int4* es4 = (const int4*)(esrc + base);
    int4 dv[4], sv[4];
    bool val[4];
#pragma unroll
    for (int k = 0; k < 4; ++k) {
      int i = t + k * 512;
      val[k] = (i < 1600);
      if (val[k]) { dv[k] = ed4[i]; sv[k] = es4[i]; }
    }
    __syncthreads();

#pragma unroll
    for (int k = 0; k < 4; ++k) if (val[k]) {
      atomicAdd(&bh[dv[k].x >> 7], 1); atomicAdd(&bh[dv[k].y >> 7], 1);
      atomicAdd(&bh[dv[k].z >> 7], 1); atomicAdd(&bh[dv[k].w >> 7], 1);
    }
    __syncthreads();

    for (int i = t; i < NB; i += 512) {
      int c = bh[i];
      gb[i] = c ? atomicAdd(&gcnt[i], c) : 0;
      bh[i] = 0;                              // reuse as local cursor
    }
    __syncthreads();

#define P1_SCATTER(d, s) do { \
      int bb = (d) >> 7; \
      int o = atomicAdd(&bh[bb], 1); \
      int pos = gb[bb] + o; \
      if (pos < CAP) ebuf[(size_t)bb * CAP + pos] = ((uint32_t)((d) & 127) << 17) | (uint32_t)(s); \
    } while (0)

#pragma unroll
    for (int k = 0; k < 4; ++k) if (val[k]) {
      P1_SCATTER(dv[k].x, sv[k].x); P1_SCATTER(dv[k].y, sv[k].y);
      P1_SCATTER(dv[k].z, sv[k].z); P1_SCATTER(dv[k].w, sv[k].w);
    }
#undef P1_SCATTER
  }
}

// ------- phase 2: inlined bucket-scan + per-bucket LDS sort -----------------
// Sort key (local_dst, src>>13); emits ssrc (coalesced) + sdeg = {start, deg}.
__global__ __launch_bounds__(256) void phase2_k(
    const uint32_t* __restrict__ ebuf, const int* __restrict__ gcnt,
    int* __restrict__ ssrc, int2* __restrict__ sdeg)
{
  __shared__ uint32_t raw[CAP];
  __shared__ int lout[CAP];
  __shared__ int cnt2[128 * 16];
  __shared__ int nd[128];
  __shared__ int psum[256];
  const int b = blockIdx.x, t = threadIdx.x;
  const int n0 = b * 128;

  // inline exclusive scan: base = sum gcnt[0..b)
  int acc = 0;
  for (int i = t; i < b; i += 256) acc += gcnt[i];
  psum[t] = acc;
  __syncthreads();
  for (int off = 128; off > 0; off >>= 1) {
    if (t < off) psum[t] += psum[t + off];
    __syncthreads();
  }
  const int base = psum[0];
  int cnt = gcnt[b]; if (cnt > CAP) cnt = CAP;

  for (int i = t; i < 128 * 16; i += 256) cnt2[i] = 0;
  __syncthreads();
  for (int i = t; i < cnt; i += 256) {
    uint32_t v = ebuf[(size_t)b * CAP + i];
    raw[i] = v;
    atomicAdd(&cnt2[(v >> 17) * 16 + ((v & 0x1FFFFu) >> SB_SHIFT)], 1);
  }
  __syncthreads();

  int deg_t = 0;
  if (t < 128) {
#pragma unroll
    for (int i = 0; i < 16; ++i) deg_t += cnt2[t * 16 + i];
    nd[t] = deg_t;
  }
  __syncthreads();
  for (int off = 1; off < 128; off <<= 1) {
    int v = 0;
    if (t < 128 && t >= off) v = nd[t - off];
    __syncthreads();
    if (t < 128) nd[t] += v;
    __syncthreads();
  }
  if (t < 128) {
    int pref = nd[t] - deg_t;               // exclusive within bucket
    if (n0 + t < NN) sdeg[n0 + t] = make_int2(base + pref, deg_t);
    int run = pref;
#pragma unroll
    for (int i = 0; i < 16; ++i) { int c = cnt2[t * 16 + i]; cnt2[t * 16 + i] = run; run += c; }
  }
  __syncthreads();
  for (int i = t; i < cnt; i += 256) {
    uint32_t v = raw[i];
    int o = atomicAdd(&cnt2[(v >> 17) * 16 + ((v & 0x1FFFFu) >> SB_SHIFT)], 1);
    lout[o] = (int)(v & 0x1FFFFu);
  }
  __syncthreads();
  for (int i = t; i < cnt; i += 256) ssrc[base + i] = lout[i];
}

// ------- aggregation: 1 wave/node, 16-lane edge groups, pipelined indices ---
// lane = q*16 + l16: q = edge slot (0..3), l16 = channel group (8 ch, uint4).
__global__ __launch_bounds__(256) void aggregate_k(
    const uint16_t* __restrict__ h, const int* __restrict__ ssrc,
    const int2* __restrict__ sdeg, uint16_t* __restrict__ agg)
{
  const int wid = (blockIdx.x * 256 + threadIdx.x) >> 6;
  if (wid >= NN) return;
  const int lane = threadIdx.x & 63;
  const int q = lane >> 4;            // edge slot within group of 4
  const int l16 = lane & 15;          // channels l16*8 .. l16*8+7
  const int2 sd = sdeg[wid];
  const int s0 = sd.x, cnt = sd.y;
  const size_t choff = (size_t)l16 * 8;
  float2 a0 = {0.f, 0.f}, a1 = {0.f, 0.f}, a2 = {0.f, 0.f}, a3 = {0.f, 0.f};

#define ACC8(v) do { \
    a0 += bf2x2((v).x); a1 += bf2x2((v).y); \
    a2 += bf2x2((v).z); a3 += bf2x2((v).w); \
  } while (0)

  if (cnt > 0) {
    // prefetch first batch's indices (clamped -> always valid)
    int e0 = ssrc[s0 + ((q      < cnt) ? q      : cnt - 1)];
    int e1 = ssrc[s0 + ((q + 4  < cnt) ? q + 4  : cnt - 1)];
    int e2 = ssrc[s0 + ((q + 8  < cnt) ? q + 8  : cnt - 1)];
    int e3 = ssrc[s0 + ((q + 12 < cnt) ? q + 12 : cnt - 1)];
    for (int j = 0; j < cnt; j += 16) {
      uint4 v0 = *(const uint4*)(h + (size_t)e0 * C + choff);
      uint4 v1 = *(const uint4*)(h + (size_t)e1 * C + choff);
      uint4 v2 = *(const uint4*)(h + (size_t)e2 * C + choff);
      uint4 v3 = *(const uint4*)(h + (size_t)e3 * C + choff);
      const int jn = j + 16;
      if (jn < cnt) {                 // prefetch next indices under the gathers
        e0 = ssrc[s0 + ((jn + q      < cnt) ? jn + q      : cnt - 1)];
        e1 = ssrc[s0 + ((jn + q + 4  < cnt) ? jn + q + 4  : cnt - 1)];
        e2 = ssrc[s0 + ((jn + q + 8  < cnt) ? jn + q + 8  : cnt - 1)];
        e3 = ssrc[s0 + ((jn + q + 12 < cnt) ? jn + q + 12 : cnt - 1)];
      }
      if (j + q      < cnt) ACC8(v0);
      if (j + q + 4  < cnt) ACC8(v1);
      if (j + q + 8  < cnt) ACC8(v2);
      if (j + q + 12 < cnt) ACC8(v3);
    }
  }
#undef ACC8

#pragma unroll
  for (int msk = 16; msk <= 32; msk <<= 1) {
    a0.x += __shfl_xor(a0.x, msk, 64); a0.y += __shfl_xor(a0.y, msk, 64);
    a1.x += __shfl_xor(a1.x, msk, 64); a1.y += __shfl_xor(a1.y, msk, 64);
    a2.x += __shfl_xor(a2.x, msk, 64); a2.y += __shfl_xor(a2.y, msk, 64);
    a3.x += __shfl_xor(a3.x, msk, 64); a3.y += __shfl_xor(a3.y, msk, 64);
  }
  if (q == 0) {
    uint4 p;
    p.x = (uint32_t)f2bf(a0.x) | ((uint32_t)f2bf(a0.y) << 16);
    p.y = (uint32_t)f2bf(a1.x) | ((uint32_t)f2bf(a1.y) << 16);
    p.z = (uint32_t)f2bf(a2.x) | ((uint32_t)f2bf(a2.y) << 16);
    p.w = (uint32_t)f2bf(a3.x) | ((uint32_t)f2bf(a3.y) << 16);
    *(uint4*)(agg + (size_t)wid * C + choff) = p;
  }
}

// ------- GEMM2 + LN: out = LN(agg@Wl^T + r)*gamma + beta; Wl in 32 KB LDS ---
// 512 thr = 8 waves x 16 rows = 128 rows/block; full occupancy.
__global__ __launch_bounds__(512) void gemm_out_k(
    const uint16_t* __restrict__ aggb, const uint16_t* __restrict__ rb,
    const uint16_t* __restrict__ wlb, const float* __restrict__ gamma,
    const float* __restrict__ beta, float* __restrict__ out)
{
  __shared__ uint8_t wl[32768];
  const int t = threadIdx.x;
#pragma unroll
  for (int qq = 0; qq < 4; ++qq) {            // stage Wl: 2048 chunks
    int ci = qq * 512 + t;
    int c = ci >> 4, k16 = ci & 15;
    *(short8*)(wl + c * 256 + ((k16 ^ (c & 15)) << 4)) = *(const short8*)(wlb + ci * 8);
  }
  __syncthreads();

  const int w = t >> 6, lane = t & 63;
  const int tile_m = blockIdx.x * 128 + w * 16;
  if (tile_m >= NN) return;
  const int r16 = lane & 15, g = lane >> 4;

  int arow = tile_m + r16; if (arow >= NN) arow = NN - 1;   // clamp OOB read
  short8 a0[4];
  const uint16_t* p0 = aggb + (size_t)arow * C + g * 8;
#pragma unroll
  for (int kk = 0; kk < 4; ++kk) a0[kk] = *(const short8*)(p0 + kk * 32);

  f32x4 acc[8];
#pragma unroll
  for (int nt = 0; nt < 8; ++nt) {
    f32x4 c4 = {0.f, 0.f, 0.f, 0.f};
    const int c = nt * 16 + r16;
    const uint8_t* rbl = wl + c * 256;
#pragma unroll
    for (int kk = 0; kk < 4; ++kk) {
      short8 b = *(const short8*)(rbl + ((((kk << 2) + g) ^ (c & 15)) << 4));
      c4 = __builtin_amdgcn_mfma_f32_16x16x32_bf16(a0[kk], b, c4, 0, 0, 0);
    }
#pragma unroll
    for (int rr = 0; rr < 4; ++rr) {          // add r = x@Wr^T + bl (from front)
      int row = tile_m + g * 4 + rr;
      int crow = row < NN ? row : NN - 1;
      c4[rr] += bf2f(rb[(size_t)crow * C + c]);
    }
    acc[nt] = c4;
  }

  // LayerNorm: each row lives in one 16-lane group -> shfl_xor 1,2,4,8
  float s1[4], s2[4];
#pragma unroll
  for (int rr = 0; rr < 4; ++rr) { s1[rr] = 0.f; s2[rr] = 0.f; }
#pragma unroll
  for (int nt = 0; nt < 8; ++nt)
#pragma unroll
    for (int rr = 0; rr < 4; ++rr) { float v = acc[nt][rr]; s1[rr] += v; s2[rr] += v * v; }
#pragma unroll
  for (int msk = 1; msk <= 8; msk <<= 1) {
#pragma unroll
    for (int rr = 0; rr < 4; ++rr) {
      s1[rr] += __shfl_xor(s1[rr], msk, 64);
      s2[rr] += __shfl_xor(s2[rr], msk, 64);
    }
  }
  float mean[4], rstd[4];
#pragma unroll
  for (int rr = 0; rr < 4; ++rr) {
    mean[rr] = s1[rr] * (1.f / C);
    float var = s2[rr] * (1.f / C) - mean[rr] * mean[rr];
    rstd[rr] = rsqrtf(var + 1e-5f);
  }
#pragma unroll
  for (int nt = 0; nt < 8; ++nt) {
    const int col = nt * 16 + r16;
    const float gmv = gamma[col], btv = beta[col];
#pragma unroll
    for (int rr = 0; rr < 4; ++rr) {
      int row = tile_m + g * 4 + rr;
      if (row < NN)
        out[(size_t)row * C + col] = (acc[nt][rr] - mean[rr]) * rstd[rr] * gmv + btv;
    }
  }
}

// ---------------- launch ----------------
extern "C" void kernel_launch(void* const* d_in, const int* in_sizes, int n_in,
                              void* d_out, int out_size, void* d_ws, size_t ws_size,
                              hipStream_t stream)
{
  const float* x        = (const float*)d_in[0];
  const int* ei         = (const int*)d_in[1];     // int32 from harness
  const float* Wp       = (const float*)d_in[2];
  const float* bp       = (const float*)d_in[3];
  const float* Wl       = (const float*)d_in[4];
  const float* bl       = (const float*)d_in[5];
  const float* Wr       = (const float*)d_in[6];
  const float* gamma    = (const float*)d_in[7];
  const float* beta     = (const float*)d_in[8];
  float* out            = (float*)d_out;

  char* ws = (char*)d_ws;
  uint16_t* rb   = (uint16_t*)(ws + 0);          // 25,600,000  r = x@Wr^T + bl (bf16)
  uint16_t* h    = (uint16_t*)(ws + 25600000);   // 25,600,000  relu(proj) bf16
  uint32_t* ebuf = (uint32_t*)(ws + 51200000);   // 12,812,288  bucketed edges
  uint16_t* aggb = (uint16_t*)(ws + 51200000);   // 25,600,000  ALIASES ebuf (dead by aggregate)
  uint16_t* wpb  = (uint16_t*)(ws + 76800000);   // 32,768
  uint16_t* wlb  = (uint16_t*)(ws + 76832768);   // 32,768
  uint16_t* wrb  = (uint16_t*)(ws + 76865536);   // 32,768
  int2* sdeg     = (int2*)(ws + 76898304);       // 800,000  {start, deg} per node
  int* gcnt      = (int*)(ws + 77698304);        // 3,128
  int* ssrc      = (int*)(ws + 78102400);        // 6,400,000

  const int* esrc = ei;        // edge_index[0]
  const int* edst = ei + NE;   // edge_index[1]

  hipMemsetAsync(gcnt, 0, NB * sizeof(int), stream);

  cast3_k<<<48, 256, 0, stream>>>(Wp, Wl, Wr, wpb, wlb, wrb);

  fused_front_k<<<MB + P1B, 512, 65536, stream>>>(
      x, wpb, wrb, bp, bl, h, rb, esrc, edst, gcnt, ebuf);

  phase2_k<<<NB, 256, 0, stream>>>(ebuf, gcnt, ssrc, sdeg);

  aggregate_k<<<(NN + 3) / 4, 256, 0, stream>>>(h, ssrc, sdeg, aggb);

  gemm_out_k<<<MB, 512, 0, stream>>>(aggb, rb, wlb, gamma, beta, out);
}